// Round 1
// baseline (165.365 us; speedup 1.0000x reference)
//
#include <hip/hip_runtime.h>
#include <math.h>
#include <stdint.h>

#define N_BINS 50
#define EDGE_N 51
#define HIST_N 52

// ws layout (uint32 units):
// [0] min_enc  [1] max_enc  [2] lower(f32) [3] upper(f32) [4] case
// [8 .. 8+4*52-1] hist: [0..51]=U_sig  [+52]=U_bkg  [+104]=V_sig  [+156]=V_bkg
//   (U = count of elements with (#edges < x) == bin  -> prefix = #{x <= edge e}
//    V = count of elements with (#edges <= x) == bin -> prefix = #{x <  edge e})
// [256 ...] xcomp float[n] (only if ws_size large enough)

__device__ __forceinline__ unsigned int f32_enc(float f) {
  unsigned int u = __float_as_uint(f);
  return (u & 0x80000000u) ? ~u : (u | 0x80000000u);
}
__device__ __forceinline__ float f32_dec(unsigned int k) {
  unsigned int u = (k & 0x80000000u) ? (k & 0x7fffffffu) : ~k;
  return __uint_as_float(u);
}

// Replicate current JAX jnp.linspace(xmin, xmax, 51) float32 semantics:
//   step = iota(50)/50 (f32 div); out = xmin*(1-step) + xmax*step (separate f32 ops);
//   endpoint concatenated exactly (= xmax).
__device__ __forceinline__ float edge_at(int e, float xmin, float xmax) {
  if (e >= N_BINS) return xmax;
  float step = __fdiv_rn((float)e, (float)N_BINS);
  float omst = __fsub_rn(1.0f, step);
  return __fadd_rn(__fmul_rn(xmin, omst), __fmul_rn(xmax, step));
}

// bce(c) = ((n_f - c)*b + c*a)/n_f in exact f32 op order (no fma contraction)
__device__ __forceinline__ float bce_f(int c, float n_f, float aC, float bC) {
  float cf = (float)c;  // exact, c < 2^24
  float t = __fadd_rn(__fmul_rn(__fsub_rn(n_f, cf), bC), __fmul_rn(cf, aC));
  return __fdiv_rn(t, n_f);
}

__device__ __forceinline__ void get_ab(float& aC, float& bC) {
  const double epsd = (double)1e-7f;      // f32(1e-7) widened
  aC = (float)(-log1p(-epsd));            // -log1p(-eps) rounded to f32
  bC = (float)(-log(epsd));               // -log(eps)   rounded to f32
}

__global__ void k_init(unsigned int* __restrict__ wsu) {
  int t = threadIdx.x;
  if (t == 0) { wsu[0] = 0xFFFFFFFFu; wsu[1] = 0u; }
  for (int i = t; i < 4 * HIST_N; i += blockDim.x) wsu[8 + i] = 0u;
}

template <int COMPACT>
__global__ void k_minmax(const float4* __restrict__ in4, int n,
                         unsigned int* __restrict__ wsu, float* __restrict__ xcomp) {
  int i = blockIdx.x * blockDim.x + threadIdx.x;
  int stride = gridDim.x * blockDim.x;
  float vmin = INFINITY, vmax = -INFINITY;
  for (; i < n; i += stride) {
    float x = in4[i].x;
    vmin = fminf(vmin, x);
    vmax = fmaxf(vmax, x);
    if (COMPACT) xcomp[i] = x;
  }
  for (int off = 32; off > 0; off >>= 1) {
    vmin = fminf(vmin, __shfl_down(vmin, off));
    vmax = fmaxf(vmax, __shfl_down(vmax, off));
  }
  __shared__ float smin[8], smax[8];
  int wid = threadIdx.x >> 6;
  if ((threadIdx.x & 63) == 0) { smin[wid] = vmin; smax[wid] = vmax; }
  __syncthreads();
  if (threadIdx.x == 0) {
    int nw = (blockDim.x + 63) >> 6;
    float m = smin[0], M = smax[0];
    for (int w = 1; w < nw; ++w) { m = fminf(m, smin[w]); M = fmaxf(M, smax[w]); }
    atomicMin(&wsu[0], f32_enc(m));
    atomicMax(&wsu[1], f32_enc(M));
  }
}

template <int COMPACT>
__global__ void k_hist(const float4* __restrict__ in4, const float* __restrict__ xcomp,
                       const int* __restrict__ tgt, int n,
                       const unsigned int* __restrict__ wsu, int* __restrict__ hist) {
  __shared__ float s_edges[EDGE_N];
  __shared__ int sh[4 * HIST_N];
  const float xmin = f32_dec(wsu[0]);
  const float xmax = f32_dec(wsu[1]);
  for (int i = threadIdx.x; i < 4 * HIST_N; i += blockDim.x) sh[i] = 0;
  if (threadIdx.x < EDGE_N) s_edges[threadIdx.x] = edge_at(threadIdx.x, xmin, xmax);
  __syncthreads();
  const float delta = __fdiv_rn(__fsub_rn(xmax, xmin), (float)N_BINS);
  const float inv_delta = (delta > 0.0f) ? (1.0f / delta) : 0.0f;  // guess only
  int i = blockIdx.x * blockDim.x + threadIdx.x;
  int stride = gridDim.x * blockDim.x;
  for (; i < n; i += stride) {
    float x = COMPACT ? xcomp[i] : in4[i].x;
    int cls = (tgt[i] == 1) ? 0 : 1;
    float t = (x - xmin) * inv_delta;
    int g = (int)t;
    g = max(0, min(g, EDGE_N));
    while (g < EDGE_N && s_edges[g] < x) ++g;   // exact: u = #edges < x
    while (g > 0 && s_edges[g - 1] >= x) --g;
    int u = g;
    int v = u + ((u < EDGE_N && s_edges[u] == x) ? 1 : 0);  // v = #edges <= x
    atomicAdd(&sh[cls * HIST_N + u], 1);
    atomicAdd(&sh[2 * HIST_N + cls * HIST_N + v], 1);
  }
  __syncthreads();
  for (int k = threadIdx.x; k < 4 * HIST_N; k += blockDim.x) {
    int val = sh[k];
    if (val) atomicAdd(&hist[k], val);
  }
}

__global__ void k_decide(unsigned int* __restrict__ wsu, const int* __restrict__ hist, int n) {
  __shared__ int s_ns_le[EDGE_N], s_ns_lt[EDGE_N], s_nb_le[EDGE_N], s_nb_lt[EDGE_N];
  __shared__ unsigned char s_mask[EDGE_N];
  __shared__ float s_edges[EDGE_N];
  __shared__ float s_rv[256];
  __shared__ int s_ri[256];
  const int tid = threadIdx.x;
  const float xmin = f32_dec(wsu[0]);
  const float xmax = f32_dec(wsu[1]);
  if (tid < EDGE_N) s_edges[tid] = edge_at(tid, xmin, xmax);
  if (tid == 0) {
    int aS = 0, aB = 0, cS = 0, cB = 0;
    for (int e = 0; e < EDGE_N; ++e) {
      aS += hist[e];
      aB += hist[HIST_N + e];
      cS += hist[2 * HIST_N + e];
      cB += hist[3 * HIST_N + e];
      s_ns_le[e] = aS; s_nb_le[e] = aB; s_ns_lt[e] = cS; s_nb_lt[e] = cB;
    }
    int h0[N_BINS], h1[N_BINS];
    bool g0[N_BINS], g1[N_BINS];
    for (int k = 0; k < N_BINS; ++k) {
      h0[k] = s_nb_le[k + 1] - s_nb_lt[k];
      h1[k] = s_ns_le[k + 1] - s_ns_lt[k];
      g0[k] = h0[k] > h1[k];
      g1[k] = h1[k] > h0[k];
    }
    for (int e = 0; e < EDGE_N; ++e) s_mask[e] = 0;
    int cnt = 0;
    for (int k = 0; k + 1 < N_BINS; ++k) {
      bool c0 = (g0[k] != g0[k + 1]) && (h0[k] > 0);
      bool c1 = (g1[k] != g1[k + 1]) && (h1[k] > 0);
      if (c0 || c1) { s_mask[k + 1] = 1; ++cnt; }
    }
    if (cnt == 1) s_mask[N_BINS] = 1;
  }
  __syncthreads();
  const int Ns = s_ns_le[EDGE_N - 1];
  const int Nb = n - Ns;
  float aC, bC;
  get_ab(aC, bC);
  const float n_f = (float)n;
  float best = INFINITY;
  int bestIdx = 0x7fffffff;
  for (int p = tid; p < EDGE_N * EDGE_N; p += blockDim.x) {
    int i = p / EDGE_N, j = p - i * EDGE_N;
    float v = INFINITY;
    if (s_mask[i] && s_mask[j] && i < j) {
      int c0 = s_ns_le[i] + (Nb - s_nb_le[i]);
      int c1 = Ns - s_ns_lt[i] + s_nb_lt[i];
      int c2 = s_ns_le[j] - s_ns_lt[i] + Nb - (s_nb_le[j] - s_nb_lt[i]);
      int c3 = s_ns_le[i] + Ns - s_ns_lt[j] + s_nb_le[j] - s_nb_lt[i];
      float L0 = bce_f(c0, n_f, aC, bC);
      float L1 = bce_f(c1, n_f, aC, bC);
      float L2 = bce_f(c2, n_f, aC, bC);
      float L3 = bce_f(c3, n_f, aC, bC);
      v = L0;
      if (L1 < v) v = L1;
      if (L2 < v) v = L2;
      if (L3 < v) v = L3;
    }
    if (v < best || (v == best && p < bestIdx)) { best = v; bestIdx = p; }
  }
  s_rv[tid] = best;
  s_ri[tid] = bestIdx;
  __syncthreads();
  for (int s = 128; s > 0; s >>= 1) {
    if (tid < s) {
      float ov = s_rv[tid + s];
      int oi = s_ri[tid + s];
      if (ov < s_rv[tid] || (ov == s_rv[tid] && oi < s_ri[tid])) {
        s_rv[tid] = ov;
        s_ri[tid] = oi;
      }
    }
    __syncthreads();
  }
  if (tid == 0) {
    int p = s_ri[0];
    int i = p / EDGE_N, j = p - i * EDGE_N;
    int c0 = s_ns_le[i] + (Nb - s_nb_le[i]);
    int c1 = Ns - s_ns_lt[i] + s_nb_lt[i];
    int c2 = s_ns_le[j] - s_ns_lt[i] + Nb - (s_nb_le[j] - s_nb_lt[i]);
    int c3 = s_ns_le[i] + Ns - s_ns_lt[j] + s_nb_le[j] - s_nb_lt[i];
    float L0 = bce_f(c0, n_f, aC, bC);
    float L1 = bce_f(c1, n_f, aC, bC);
    float L2 = bce_f(c2, n_f, aC, bC);
    float L3 = bce_f(c3, n_f, aC, bC);
    int cs = 0;
    float m = L0;
    if (L1 < m) { m = L1; cs = 1; }
    if (L2 < m) { m = L2; cs = 2; }
    if (L3 < m) { m = L3; cs = 3; }
    ((float*)wsu)[2] = s_edges[i];
    ((float*)wsu)[3] = s_edges[j];
    ((int*)wsu)[4] = cs;
  }
}

template <int COMPACT>
__global__ void k_pred(const float4* __restrict__ in4, const float* __restrict__ xcomp,
                       int n, const unsigned int* __restrict__ wsu, int* __restrict__ out) {
  const float lower = ((const float*)wsu)[2];
  const float upper = ((const float*)wsu)[3];
  const int cs = ((const int*)wsu)[4];
  int i = blockIdx.x * blockDim.x + threadIdx.x;
  int stride = gridDim.x * blockDim.x;
  for (; i < n; i += stride) {
    float x = COMPACT ? xcomp[i] : in4[i].x;
    bool p;
    if (cs == 0) p = (x <= lower);
    else if (cs == 1) p = (x >= lower);
    else if (cs == 2) p = (x >= lower) && (x <= upper);
    else p = (x <= lower) || (x >= upper);
    out[i] = p ? 1 : 0;
  }
}

extern "C" void kernel_launch(void* const* d_in, const int* in_sizes, int n_in,
                              void* d_out, int out_size, void* d_ws, size_t ws_size,
                              hipStream_t stream) {
  const float4* in4 = (const float4*)d_in[0];
  const int* tgt = (const int*)d_in[1];
  const int n = in_sizes[1];
  int* out = (int*)d_out;
  unsigned int* wsu = (unsigned int*)d_ws;
  int* hist = (int*)(wsu + 8);
  float* xcomp = (float*)(wsu + 256);
  const bool compact = ws_size >= (size_t)1024 + (size_t)n * 4u;

  k_init<<<1, 256, 0, stream>>>(wsu);
  const int blocks = 2048;
  if (compact) {
    k_minmax<1><<<blocks, 256, 0, stream>>>(in4, n, wsu, xcomp);
    k_hist<1><<<blocks, 256, 0, stream>>>(in4, xcomp, tgt, n, wsu, hist);
  } else {
    k_minmax<0><<<blocks, 256, 0, stream>>>(in4, n, wsu, nullptr);
    k_hist<0><<<blocks, 256, 0, stream>>>(in4, nullptr, tgt, n, wsu, hist);
  }
  k_decide<<<1, 256, 0, stream>>>(wsu, hist, n);
  if (compact) {
    k_pred<1><<<blocks, 256, 0, stream>>>(in4, xcomp, n, wsu, out);
  } else {
    k_pred<0><<<blocks, 256, 0, stream>>>(in4, nullptr, n, wsu, out);
  }
}

// Round 2
// 151.172 us; speedup vs baseline: 1.0939x; 1.0939x over previous
//
#include <hip/hip_runtime.h>
#include <math.h>
#include <stdint.h>

#define N_BINS 50
#define EDGE_N 51
#define HIST_N 52
#define NBLK 2048
#define NTHR 256

// ws layout (uint32 units):
// [0] min_enc  [1] max_enc  [2] lower(f32) [3] upper(f32) [4] case
// [8 .. 8+2*52-1]          U hist: [0..51]=U_sig  [+52]=U_bkg
//   (U = count of elements with (#edges < x) == bin -> prefix = #{x <= edge e})
// [8+104 .. 8+104+2*51-1]  E hist: count of x exactly equal to edge u, per class
//   (ns_lt[e] = ns_le[e] - E_sig[e]; nb_lt[e] = nb_le[e] - E_bkg[e])
// [256 ...] xcomp float[n] (only if ws_size large enough)

__device__ __forceinline__ unsigned int f32_enc(float f) {
  unsigned int u = __float_as_uint(f);
  return (u & 0x80000000u) ? ~u : (u | 0x80000000u);
}
__device__ __forceinline__ float f32_dec(unsigned int k) {
  unsigned int u = (k & 0x80000000u) ? (k & 0x7fffffffu) : ~k;
  return __uint_as_float(u);
}

// jnp.linspace(xmin, xmax, 51) float32 semantics:
//   step = e/50 (f32 div); out = xmin*(1-step) + xmax*step; endpoint = xmax exactly.
__device__ __forceinline__ float edge_at(int e, float xmin, float xmax) {
  if (e >= N_BINS) return xmax;
  float step = __fdiv_rn((float)e, (float)N_BINS);
  float omst = __fsub_rn(1.0f, step);
  return __fadd_rn(__fmul_rn(xmin, omst), __fmul_rn(xmax, step));
}

// bce(c) = ((n_f - c)*b + c*a)/n_f in exact f32 op order (no fma contraction)
__device__ __forceinline__ float bce_f(int c, float n_f, float aC, float bC) {
  float cf = (float)c;  // exact, c < 2^24
  float t = __fadd_rn(__fmul_rn(__fsub_rn(n_f, cf), bC), __fmul_rn(cf, aC));
  return __fdiv_rn(t, n_f);
}

__device__ __forceinline__ void get_ab(float& aC, float& bC) {
  const double epsd = (double)1e-7f;
  aC = (float)(-log1p(-epsd));
  bC = (float)(-log(epsd));
}

__global__ void k_init(unsigned int* __restrict__ wsu) {
  int t = threadIdx.x;
  if (t == 0) { wsu[0] = 0xFFFFFFFFu; wsu[1] = 0u; }
  for (int i = t; i < 2 * HIST_N + 2 * EDGE_N; i += blockDim.x) wsu[8 + i] = 0u;
}

template <int COMPACT>
__global__ void k_minmax(const float4* __restrict__ in4, int n,
                         unsigned int* __restrict__ wsu, float* __restrict__ xc) {
  float4* __restrict__ xc4 = (float4*)xc;
  const int nv = n >> 2;
  const int gid = blockIdx.x * blockDim.x + threadIdx.x;
  const int stride = gridDim.x * blockDim.x;
  float vmin = INFINITY, vmax = -INFINITY;
  for (int iv = gid; iv < nv; iv += stride) {
    float4 a = in4[4 * iv + 0];
    float4 b = in4[4 * iv + 1];
    float4 c = in4[4 * iv + 2];
    float4 d = in4[4 * iv + 3];
    float x0 = a.x, x1 = b.x, x2 = c.x, x3 = d.x;
    vmin = fminf(fminf(vmin, fminf(x0, x1)), fminf(x2, x3));
    vmax = fmaxf(fmaxf(vmax, fmaxf(x0, x1)), fmaxf(x2, x3));
    if (COMPACT) xc4[iv] = make_float4(x0, x1, x2, x3);
  }
  const int base = nv << 2;
  if (blockIdx.x == 0 && threadIdx.x < (n - base)) {
    float x = in4[base + threadIdx.x].x;
    vmin = fminf(vmin, x);
    vmax = fmaxf(vmax, x);
    if (COMPACT) xc[base + threadIdx.x] = x;
  }
  for (int off = 32; off > 0; off >>= 1) {
    vmin = fminf(vmin, __shfl_down(vmin, off));
    vmax = fmaxf(vmax, __shfl_down(vmax, off));
  }
  __shared__ float smin[NTHR / 64], smax[NTHR / 64];
  int wid = threadIdx.x >> 6;
  if ((threadIdx.x & 63) == 0) { smin[wid] = vmin; smax[wid] = vmax; }
  __syncthreads();
  if (threadIdx.x == 0) {
    int nw = blockDim.x >> 6;
    float m = smin[0], M = smax[0];
    for (int w = 1; w < nw; ++w) { m = fminf(m, smin[w]); M = fmaxf(M, smax[w]); }
    atomicMin(&wsu[0], f32_enc(m));
    atomicMax(&wsu[1], f32_enc(M));
  }
}

template <int COMPACT>
__global__ void k_hist(const float4* __restrict__ in4, const float* __restrict__ xc,
                       const int* __restrict__ tgt, int n,
                       const unsigned int* __restrict__ wsu,
                       int* __restrict__ histU, int* __restrict__ histE) {
  __shared__ float s_edges[EDGE_N];
  __shared__ int shU[2 * HIST_N];
  __shared__ int shE[2 * EDGE_N];
  const float xmin = f32_dec(wsu[0]);
  const float xmax = f32_dec(wsu[1]);
  for (int i = threadIdx.x; i < 2 * HIST_N; i += blockDim.x) shU[i] = 0;
  for (int i = threadIdx.x; i < 2 * EDGE_N; i += blockDim.x) shE[i] = 0;
  if (threadIdx.x < EDGE_N) s_edges[threadIdx.x] = edge_at(threadIdx.x, xmin, xmax);
  __syncthreads();
  const float delta = __fdiv_rn(__fsub_rn(xmax, xmin), (float)N_BINS);
  const float inv_delta = (delta > 0.0f) ? (1.0f / delta) : 0.0f;  // guess only
  const float4* __restrict__ xc4 = (const float4*)xc;
  const int4* __restrict__ tgt4 = (const int4*)tgt;
  const int nv = n >> 2;
  const int gid = blockIdx.x * blockDim.x + threadIdx.x;
  const int stride = gridDim.x * blockDim.x;
  for (int iv = gid; iv < nv; iv += stride) {
    float xs[4];
    if (COMPACT) {
      float4 v = xc4[iv];
      xs[0] = v.x; xs[1] = v.y; xs[2] = v.z; xs[3] = v.w;
    } else {
      xs[0] = in4[4 * iv + 0].x; xs[1] = in4[4 * iv + 1].x;
      xs[2] = in4[4 * iv + 2].x; xs[3] = in4[4 * iv + 3].x;
    }
    int4 tv = tgt4[iv];
    int ts[4] = {tv.x, tv.y, tv.z, tv.w};
#pragma unroll
    for (int k = 0; k < 4; ++k) {
      float x = xs[k];
      int cls = (ts[k] == 1) ? 0 : 1;
      int g = (int)((x - xmin) * inv_delta);
      g = max(0, min(g, EDGE_N));
      while (g < EDGE_N && s_edges[g] < x) ++g;   // exact: u = #edges < x
      while (g > 0 && s_edges[g - 1] >= x) --g;
      atomicAdd(&shU[cls * HIST_N + g], 1);
      if (g < EDGE_N && s_edges[g] == x) atomicAdd(&shE[cls * EDGE_N + g], 1);
    }
  }
  const int base = nv << 2;
  if (blockIdx.x == 0 && threadIdx.x < (n - base)) {
    int i = base + threadIdx.x;
    float x = COMPACT ? xc[i] : in4[i].x;
    int cls = (tgt[i] == 1) ? 0 : 1;
    int g = (int)((x - xmin) * inv_delta);
    g = max(0, min(g, EDGE_N));
    while (g < EDGE_N && s_edges[g] < x) ++g;
    while (g > 0 && s_edges[g - 1] >= x) --g;
    atomicAdd(&shU[cls * HIST_N + g], 1);
    if (g < EDGE_N && s_edges[g] == x) atomicAdd(&shE[cls * EDGE_N + g], 1);
  }
  __syncthreads();
  for (int k = threadIdx.x; k < 2 * HIST_N; k += blockDim.x) {
    int val = shU[k];
    if (val) atomicAdd(&histU[k], val);
  }
  for (int k = threadIdx.x; k < 2 * EDGE_N; k += blockDim.x) {
    int val = shE[k];
    if (val) atomicAdd(&histE[k], val);
  }
}

__global__ void k_decide(unsigned int* __restrict__ wsu, const int* __restrict__ histU,
                         const int* __restrict__ histE, int n) {
  __shared__ int s_ns_le[EDGE_N], s_ns_lt[EDGE_N], s_nb_le[EDGE_N], s_nb_lt[EDGE_N];
  __shared__ unsigned char s_mask[EDGE_N];
  __shared__ float s_edges[EDGE_N];
  __shared__ float s_rv[256];
  __shared__ int s_ri[256];
  const int tid = threadIdx.x;
  const float xmin = f32_dec(wsu[0]);
  const float xmax = f32_dec(wsu[1]);
  if (tid < EDGE_N) s_edges[tid] = edge_at(tid, xmin, xmax);
  if (tid == 0) {
    int aS = 0, aB = 0;
    for (int e = 0; e < EDGE_N; ++e) {
      aS += histU[e];
      aB += histU[HIST_N + e];
      s_ns_le[e] = aS;
      s_nb_le[e] = aB;
      s_ns_lt[e] = aS - histE[e];
      s_nb_lt[e] = aB - histE[EDGE_N + e];
    }
    int h0[N_BINS], h1[N_BINS];
    bool g0[N_BINS], g1[N_BINS];
    for (int k = 0; k < N_BINS; ++k) {
      h0[k] = s_nb_le[k + 1] - s_nb_lt[k];
      h1[k] = s_ns_le[k + 1] - s_ns_lt[k];
      g0[k] = h0[k] > h1[k];
      g1[k] = h1[k] > h0[k];
    }
    for (int e = 0; e < EDGE_N; ++e) s_mask[e] = 0;
    int cnt = 0;
    for (int k = 0; k + 1 < N_BINS; ++k) {
      bool c0 = (g0[k] != g0[k + 1]) && (h0[k] > 0);
      bool c1 = (g1[k] != g1[k + 1]) && (h1[k] > 0);
      if (c0 || c1) { s_mask[k + 1] = 1; ++cnt; }
    }
    if (cnt == 1) s_mask[N_BINS] = 1;
  }
  __syncthreads();
  const int Ns = s_ns_le[EDGE_N - 1];
  const int Nb = n - Ns;
  float aC, bC;
  get_ab(aC, bC);
  const float n_f = (float)n;
  float best = INFINITY;
  int bestIdx = 0x7fffffff;
  for (int p = tid; p < EDGE_N * EDGE_N; p += blockDim.x) {
    int i = p / EDGE_N, j = p - i * EDGE_N;
    float v = INFINITY;
    if (s_mask[i] && s_mask[j] && i < j) {
      int c0 = s_ns_le[i] + (Nb - s_nb_le[i]);
      int c1 = Ns - s_ns_lt[i] + s_nb_lt[i];
      int c2 = s_ns_le[j] - s_ns_lt[i] + Nb - (s_nb_le[j] - s_nb_lt[i]);
      int c3 = s_ns_le[i] + Ns - s_ns_lt[j] + s_nb_le[j] - s_nb_lt[i];
      float L0 = bce_f(c0, n_f, aC, bC);
      float L1 = bce_f(c1, n_f, aC, bC);
      float L2 = bce_f(c2, n_f, aC, bC);
      float L3 = bce_f(c3, n_f, aC, bC);
      v = L0;
      if (L1 < v) v = L1;
      if (L2 < v) v = L2;
      if (L3 < v) v = L3;
    }
    if (v < best || (v == best && p < bestIdx)) { best = v; bestIdx = p; }
  }
  s_rv[tid] = best;
  s_ri[tid] = bestIdx;
  __syncthreads();
  for (int s = 128; s > 0; s >>= 1) {
    if (tid < s) {
      float ov = s_rv[tid + s];
      int oi = s_ri[tid + s];
      if (ov < s_rv[tid] || (ov == s_rv[tid] && oi < s_ri[tid])) {
        s_rv[tid] = ov;
        s_ri[tid] = oi;
      }
    }
    __syncthreads();
  }
  if (tid == 0) {
    int p = s_ri[0];
    int i = p / EDGE_N, j = p - i * EDGE_N;
    int c0 = s_ns_le[i] + (Nb - s_nb_le[i]);
    int c1 = Ns - s_ns_lt[i] + s_nb_lt[i];
    int c2 = s_ns_le[j] - s_ns_lt[i] + Nb - (s_nb_le[j] - s_nb_lt[i]);
    int c3 = s_ns_le[i] + Ns - s_ns_lt[j] + s_nb_le[j] - s_nb_lt[i];
    float L0 = bce_f(c0, n_f, aC, bC);
    float L1 = bce_f(c1, n_f, aC, bC);
    float L2 = bce_f(c2, n_f, aC, bC);
    float L3 = bce_f(c3, n_f, aC, bC);
    int cs = 0;
    float m = L0;
    if (L1 < m) { m = L1; cs = 1; }
    if (L2 < m) { m = L2; cs = 2; }
    if (L3 < m) { m = L3; cs = 3; }
    ((float*)wsu)[2] = s_edges[i];
    ((float*)wsu)[3] = s_edges[j];
    ((int*)wsu)[4] = cs;
  }
}

template <int COMPACT>
__global__ void k_pred(const float4* __restrict__ in4, const float* __restrict__ xc,
                       int n, const unsigned int* __restrict__ wsu, int* __restrict__ out) {
  const float lower = ((const float*)wsu)[2];
  const float upper = ((const float*)wsu)[3];
  const int cs = ((const int*)wsu)[4];
  const float4* __restrict__ xc4 = (const float4*)xc;
  int4* __restrict__ out4 = (int4*)out;
  const int nv = n >> 2;
  const int gid = blockIdx.x * blockDim.x + threadIdx.x;
  const int stride = gridDim.x * blockDim.x;
  for (int iv = gid; iv < nv; iv += stride) {
    float xs[4];
    if (COMPACT) {
      float4 v = xc4[iv];
      xs[0] = v.x; xs[1] = v.y; xs[2] = v.z; xs[3] = v.w;
    } else {
      xs[0] = in4[4 * iv + 0].x; xs[1] = in4[4 * iv + 1].x;
      xs[2] = in4[4 * iv + 2].x; xs[3] = in4[4 * iv + 3].x;
    }
    int r[4];
#pragma unroll
    for (int k = 0; k < 4; ++k) {
      float x = xs[k];
      bool p;
      if (cs == 0) p = (x <= lower);
      else if (cs == 1) p = (x >= lower);
      else if (cs == 2) p = (x >= lower) && (x <= upper);
      else p = (x <= lower) || (x >= upper);
      r[k] = p ? 1 : 0;
    }
    out4[iv] = make_int4(r[0], r[1], r[2], r[3]);
  }
  const int base = nv << 2;
  if (blockIdx.x == 0 && threadIdx.x < (n - base)) {
    int i = base + threadIdx.x;
    float x = COMPACT ? xc[i] : in4[i].x;
    bool p;
    if (cs == 0) p = (x <= lower);
    else if (cs == 1) p = (x >= lower);
    else if (cs == 2) p = (x >= lower) && (x <= upper);
    else p = (x <= lower) || (x >= upper);
    out[i] = p ? 1 : 0;
  }
}

extern "C" void kernel_launch(void* const* d_in, const int* in_sizes, int n_in,
                              void* d_out, int out_size, void* d_ws, size_t ws_size,
                              hipStream_t stream) {
  const float4* in4 = (const float4*)d_in[0];
  const int* tgt = (const int*)d_in[1];
  const int n = in_sizes[1];
  int* out = (int*)d_out;
  unsigned int* wsu = (unsigned int*)d_ws;
  int* histU = (int*)(wsu + 8);
  int* histE = (int*)(wsu + 8 + 2 * HIST_N);
  float* xcomp = (float*)(wsu + 256);
  const bool compact = ws_size >= (size_t)1024 + (size_t)n * 4u;

  k_init<<<1, 256, 0, stream>>>(wsu);
  if (compact) {
    k_minmax<1><<<NBLK, NTHR, 0, stream>>>(in4, n, wsu, xcomp);
    k_hist<1><<<NBLK, NTHR, 0, stream>>>(in4, xcomp, tgt, n, wsu, histU, histE);
  } else {
    k_minmax<0><<<NBLK, NTHR, 0, stream>>>(in4, n, wsu, nullptr);
    k_hist<0><<<NBLK, NTHR, 0, stream>>>(in4, nullptr, tgt, n, wsu, histU, histE);
  }
  k_decide<<<1, 256, 0, stream>>>(wsu, histU, histE, n);
  if (compact) {
    k_pred<1><<<NBLK, NTHR, 0, stream>>>(in4, xcomp, n, wsu, out);
  } else {
    k_pred<0><<<NBLK, NTHR, 0, stream>>>(in4, nullptr, n, wsu, out);
  }
}